// Round 1
// baseline (1498.744 us; speedup 1.0000x reference)
//
#include <hip/hip_runtime.h>

#define N_SIZE 4096
#define N_STEPS 512
#define WROW 8192
#define THRESH 10.0f

// ---------------- transpose: WsT[s][o] = W[o*8192 + 4096 + s] ----------------
__global__ __launch_bounds__(256) void k_transpose(const float* __restrict__ W,
                                                   float* __restrict__ WsT) {
    __shared__ float tile[32][33];
    const int bs = blockIdx.x * 32;
    const int bo = blockIdx.y * 32;
    const int tx = threadIdx.x;   // 0..31
    const int ty = threadIdx.y;   // 0..7
#pragma unroll
    for (int j = 0; j < 4; ++j) {
        const int o = bo + ty + j * 8;
        tile[ty + j * 8][tx] = W[(size_t)o * WROW + N_SIZE + bs + tx];
    }
    __syncthreads();
#pragma unroll
    for (int j = 0; j < 4; ++j) {
        const int s = bs + ty + j * 8;
        WsT[(size_t)s * N_SIZE + bo + tx] = tile[tx][ty + j * 8];
    }
}

// ---------------- GEMM: C[t][o] = sum_k x[t][k] * W[o][k]  (Wx half) --------
#define BM 64
#define BN 128
#define BK 16

__global__ __launch_bounds__(256) void k_gemm(const float* __restrict__ x,
                                              const float* __restrict__ W,
                                              float* __restrict__ C) {
    __shared__ float As[BK][BM + 4];
    __shared__ float Bs[BK][BN + 4];
    const int tid = threadIdx.x;
    const int bm = blockIdx.y * BM;
    const int bn = blockIdx.x * BN;
    const int m0 = (tid >> 4) << 2;    // 16 row-groups * 4 rows
    const int n0 = (tid & 15) << 3;    // 16 col-groups * 8 cols
    const int lr = tid >> 2;           // 0..63
    const int lc = (tid & 3) << 2;     // 0,4,8,12

    float acc[4][8];
#pragma unroll
    for (int i = 0; i < 4; ++i)
#pragma unroll
        for (int j = 0; j < 8; ++j) acc[i][j] = 0.f;

    for (int kb = 0; kb < N_SIZE; kb += BK) {
        const float4 a  = *(const float4*)&x[(size_t)(bm + lr) * N_SIZE + kb + lc];
        const float4 b0 = *(const float4*)&W[(size_t)(bn + lr) * WROW + kb + lc];
        const float4 b1 = *(const float4*)&W[(size_t)(bn + 64 + lr) * WROW + kb + lc];
        __syncthreads();
        As[lc + 0][lr] = a.x;  As[lc + 1][lr] = a.y;
        As[lc + 2][lr] = a.z;  As[lc + 3][lr] = a.w;
        Bs[lc + 0][lr] = b0.x; Bs[lc + 1][lr] = b0.y;
        Bs[lc + 2][lr] = b0.z; Bs[lc + 3][lr] = b0.w;
        Bs[lc + 0][64 + lr] = b1.x; Bs[lc + 1][64 + lr] = b1.y;
        Bs[lc + 2][64 + lr] = b1.z; Bs[lc + 3][64 + lr] = b1.w;
        __syncthreads();
#pragma unroll
        for (int k = 0; k < BK; ++k) {
            const float4 av  = *(const float4*)&As[k][m0];
            const float4 bv0 = *(const float4*)&Bs[k][n0];
            const float4 bv1 = *(const float4*)&Bs[k][n0 + 4];
            const float am[4]  = {av.x, av.y, av.z, av.w};
            const float bnv[8] = {bv0.x, bv0.y, bv0.z, bv0.w,
                                  bv1.x, bv1.y, bv1.z, bv1.w};
#pragma unroll
            for (int i = 0; i < 4; ++i)
#pragma unroll
                for (int j = 0; j < 8; ++j)
                    acc[i][j] = fmaf(am[i], bnv[j], acc[i][j]);
        }
    }
#pragma unroll
    for (int i = 0; i < 4; ++i) {
        float* cp = &C[(size_t)(bm + m0 + i) * N_SIZE + bn + n0];
        const float4 o0 = {acc[i][0], acc[i][1], acc[i][2], acc[i][3]};
        const float4 o1 = {acc[i][4], acc[i][5], acc[i][6], acc[i][7]};
        *(float4*)&cp[0] = o0;
        *(float4*)&cp[4] = o1;
    }
}

// ---------------- persistent single-workgroup scan ----------------
// mem_out initially holds cur_x (written by k_gemm); row t is read then
// overwritten with mem[t] in place. Spike list rebuilt per step via sorted,
// deterministic ballot compaction.
template <int USE_WST>
__global__ __launch_bounds__(1024) void k_scan(const float* __restrict__ WsT,
                                               const float* __restrict__ W,
                                               float* __restrict__ spk_out,
                                               float* __restrict__ mem_out) {
    __shared__ int lists[2][N_SIZE];
    __shared__ int wcnt[16];
    const int tid  = threadIdx.x;
    const int wave = tid >> 6;
    const int lane = tid & 63;
    const int base = tid << 2;          // this thread's 4 neurons: base..base+3

    float4 mem = {0.f, 0.f, 0.f, 0.f};
    int cnt = 0;
    int cur = 0;

    for (int t = 0; t < N_STEPS; ++t) {
        float* mrow = &mem_out[(size_t)t * N_SIZE + base];
        float4 c = *(const float4*)mrow;           // cur_x[t] slice

        const int* lst = lists[cur];
        int i = 0;
        for (; i + 2 <= cnt; i += 2) {
            const int s0 = lst[i];
            const int s1 = lst[i + 1];
            float4 w0, w1;
            if (USE_WST) {
                w0 = *(const float4*)&WsT[(size_t)s0 * N_SIZE + base];
                w1 = *(const float4*)&WsT[(size_t)s1 * N_SIZE + base];
            } else {
                w0.x = W[(size_t)(base + 0) * WROW + N_SIZE + s0];
                w0.y = W[(size_t)(base + 1) * WROW + N_SIZE + s0];
                w0.z = W[(size_t)(base + 2) * WROW + N_SIZE + s0];
                w0.w = W[(size_t)(base + 3) * WROW + N_SIZE + s0];
                w1.x = W[(size_t)(base + 0) * WROW + N_SIZE + s1];
                w1.y = W[(size_t)(base + 1) * WROW + N_SIZE + s1];
                w1.z = W[(size_t)(base + 2) * WROW + N_SIZE + s1];
                w1.w = W[(size_t)(base + 3) * WROW + N_SIZE + s1];
            }
            c.x += w0.x + w1.x;
            c.y += w0.y + w1.y;
            c.z += w0.z + w1.z;
            c.w += w0.w + w1.w;
        }
        if (i < cnt) {
            const int s0 = lst[i];
            float4 w0;
            if (USE_WST) {
                w0 = *(const float4*)&WsT[(size_t)s0 * N_SIZE + base];
            } else {
                w0.x = W[(size_t)(base + 0) * WROW + N_SIZE + s0];
                w0.y = W[(size_t)(base + 1) * WROW + N_SIZE + s0];
                w0.z = W[(size_t)(base + 2) * WROW + N_SIZE + s0];
                w0.w = W[(size_t)(base + 3) * WROW + N_SIZE + s0];
            }
            c.x += w0.x; c.y += w0.y; c.z += w0.z; c.w += w0.w;
        }

        mem.x += c.x; mem.y += c.y; mem.z += c.z; mem.w += c.w;

        const bool s0 = mem.x > THRESH;
        const bool s1 = mem.y > THRESH;
        const bool s2 = mem.z > THRESH;
        const bool s3 = mem.w > THRESH;
        if (s0) mem.x -= THRESH;
        if (s1) mem.y -= THRESH;
        if (s2) mem.z -= THRESH;
        if (s3) mem.w -= THRESH;

        const float4 spkv = {s0 ? 1.f : 0.f, s1 ? 1.f : 0.f,
                             s2 ? 1.f : 0.f, s3 ? 1.f : 0.f};
        *(float4*)&spk_out[(size_t)t * N_SIZE + base] = spkv;
        *(float4*)mrow = mem;

        // ---- deterministic sorted compaction of next spike list ----
        const unsigned long long b0 = __ballot(s0);
        const unsigned long long b1 = __ballot(s1);
        const unsigned long long b2 = __ballot(s2);
        const unsigned long long b3 = __ballot(s3);
        const unsigned long long below =
            (lane == 0) ? 0ULL : (~0ULL >> (64 - lane));
        const int pre = __popcll(b0 & below) + __popcll(b1 & below) +
                        __popcll(b2 & below) + __popcll(b3 & below);
        if (lane == 0)
            wcnt[wave] = __popcll(b0) + __popcll(b1) + __popcll(b2) + __popcll(b3);
        __syncthreads();

        int woff = 0, total = 0;
#pragma unroll
        for (int wv = 0; wv < 16; ++wv) {
            const int cw = wcnt[wv];
            woff += (wv < wave) ? cw : 0;
            total += cw;
        }
        int* nxt = lists[cur ^ 1];
        int off = woff + pre;
        if (s0) nxt[off++] = base;
        if (s1) nxt[off++] = base + 1;
        if (s2) nxt[off++] = base + 2;
        if (s3) nxt[off++] = base + 3;
        __syncthreads();

        cnt = total;
        cur ^= 1;
    }
}

extern "C" void kernel_launch(void* const* d_in, const int* in_sizes, int n_in,
                              void* d_out, int out_size, void* d_ws, size_t ws_size,
                              hipStream_t stream) {
    const float* x = (const float*)d_in[0];
    const float* W = (const float*)d_in[1];
    float* spk_out = (float*)d_out;
    float* mem_out = spk_out + (size_t)N_STEPS * N_SIZE;
    float* WsT = (float*)d_ws;
    const bool use_wst = ws_size >= (size_t)N_SIZE * N_SIZE * sizeof(float);

    // cur_x staged into the mem_rec half of d_out (overwritten in place by scan)
    k_gemm<<<dim3(N_SIZE / BN, N_STEPS / BM), 256, 0, stream>>>(x, W, mem_out);

    if (use_wst) {
        k_transpose<<<dim3(N_SIZE / 32, N_SIZE / 32), dim3(32, 8), 0, stream>>>(W, WsT);
        k_scan<1><<<1, 1024, 0, stream>>>(WsT, W, spk_out, mem_out);
    } else {
        k_scan<0><<<1, 1024, 0, stream>>>(WsT, W, spk_out, mem_out);
    }
}

// Round 2
// 1498.552 us; speedup vs baseline: 1.0001x; 1.0001x over previous
//
#include <hip/hip_runtime.h>

#define N_SIZE 4096
#define N_STEPS 512
#define WROW 8192
#define THRESH 10.0f

// ---------------- transpose: WsT[s][o] = W[o*8192 + 4096 + s] ----------------
__global__ __launch_bounds__(256) void k_transpose(const float* __restrict__ W,
                                                   float* __restrict__ WsT) {
    __shared__ float tile[32][33];
    const int bs = blockIdx.x * 32;
    const int bo = blockIdx.y * 32;
    const int tx = threadIdx.x;   // 0..31
    const int ty = threadIdx.y;   // 0..7
#pragma unroll
    for (int j = 0; j < 4; ++j)
        tile[ty + j * 8][tx] = W[(size_t)(bo + ty + j * 8) * WROW + N_SIZE + bs + tx];
    __syncthreads();
#pragma unroll
    for (int j = 0; j < 4; ++j)
        WsT[(size_t)(bs + ty + j * 8) * N_SIZE + bo + tx] = tile[tx][ty + j * 8];
}

// ---------------- GEMM: C[t][o] = sum_k x[t][k] * W[o][k], split-K=2 --------
#define BM 64
#define BN 128
#define BK 16
#define KHALF (N_SIZE / 2)
#define ALD 68    // 64+4: 2-way max bank conflicts on scatter writes (free)
#define BLD 132   // 128+4

#define F4E(v, j) ((j) == 0 ? (v).x : (j) == 1 ? (v).y : (j) == 2 ? (v).z : (v).w)

__global__ __launch_bounds__(128) void k_gemm(const float* __restrict__ x,
                                              const float* __restrict__ W,
                                              float* __restrict__ dst0,
                                              float* __restrict__ dst1) {
    __shared__ float As[BK][ALD];
    __shared__ float Bs[BK][BLD];
    const int tid = threadIdx.x;
    const int bm = blockIdx.y * BM;
    const int bn = blockIdx.x * BN;
    const int kb0 = blockIdx.z * KHALF;
    float* dst = blockIdx.z ? dst1 : dst0;

    const int m0 = (tid >> 4) << 3;   // 8 m-groups * 8 rows
    const int n0 = (tid & 15) << 2;   // 16 n-groups * 4 cols (+64 second half)

    const int ar = tid >> 2;          // 0..31
    const int ac = (tid & 3) << 2;    // 0,4,8,12
    const float* Ap = &x[(size_t)(bm + ar) * N_SIZE + kb0 + ac];
    const float* Bp = &W[(size_t)(bn + ar) * WROW + kb0 + ac];

    float4 pa0 = *(const float4*)&Ap[0];
    float4 pa1 = *(const float4*)&Ap[(size_t)32 * N_SIZE];
    float4 pb0 = *(const float4*)&Bp[0];
    float4 pb1 = *(const float4*)&Bp[(size_t)32 * WROW];
    float4 pb2 = *(const float4*)&Bp[(size_t)64 * WROW];
    float4 pb3 = *(const float4*)&Bp[(size_t)96 * WROW];

    float acc[8][8];
#pragma unroll
    for (int i = 0; i < 8; ++i)
#pragma unroll
        for (int j = 0; j < 8; ++j) acc[i][j] = 0.f;

    const int nkt = KHALF / BK;
    for (int kt = 0; kt < nkt; ++kt) {
        __syncthreads();
#pragma unroll
        for (int j = 0; j < 4; ++j) {
            As[ac + j][ar]      = F4E(pa0, j);
            As[ac + j][ar + 32] = F4E(pa1, j);
            Bs[ac + j][ar]      = F4E(pb0, j);
            Bs[ac + j][ar + 32] = F4E(pb1, j);
            Bs[ac + j][ar + 64] = F4E(pb2, j);
            Bs[ac + j][ar + 96] = F4E(pb3, j);
        }
        __syncthreads();
        if (kt + 1 < nkt) {
            const float* Ap2 = Ap + (size_t)(kt + 1) * BK;
            const float* Bp2 = Bp + (size_t)(kt + 1) * BK;
            pa0 = *(const float4*)&Ap2[0];
            pa1 = *(const float4*)&Ap2[(size_t)32 * N_SIZE];
            pb0 = *(const float4*)&Bp2[0];
            pb1 = *(const float4*)&Bp2[(size_t)32 * WROW];
            pb2 = *(const float4*)&Bp2[(size_t)64 * WROW];
            pb3 = *(const float4*)&Bp2[(size_t)96 * WROW];
        }
#pragma unroll
        for (int k = 0; k < BK; ++k) {
            const float4 a0 = *(const float4*)&As[k][m0];
            const float4 a1 = *(const float4*)&As[k][m0 + 4];
            const float4 b0 = *(const float4*)&Bs[k][n0];
            const float4 b1 = *(const float4*)&Bs[k][n0 + 64];
            const float av[8] = {a0.x, a0.y, a0.z, a0.w, a1.x, a1.y, a1.z, a1.w};
            const float bv[8] = {b0.x, b0.y, b0.z, b0.w, b1.x, b1.y, b1.z, b1.w};
#pragma unroll
            for (int i = 0; i < 8; ++i)
#pragma unroll
                for (int j = 0; j < 8; ++j)
                    acc[i][j] = fmaf(av[i], bv[j], acc[i][j]);
        }
    }
#pragma unroll
    for (int i = 0; i < 8; ++i) {
        float* cp = &dst[(size_t)(bm + m0 + i) * N_SIZE + bn];
        const float4 o0 = {acc[i][0], acc[i][1], acc[i][2], acc[i][3]};
        const float4 o1 = {acc[i][4], acc[i][5], acc[i][6], acc[i][7]};
        *(float4*)&cp[n0] = o0;
        *(float4*)&cp[n0 + 64] = o1;
    }
}

// ---------------- deterministic split-K reduce: acc += part ----------------
__global__ __launch_bounds__(256) void k_reduce(float* __restrict__ acc,
                                                const float* __restrict__ part) {
    const size_t i = ((size_t)blockIdx.x * 256 + threadIdx.x) * 4;
    const float4 a = *(const float4*)&acc[i];
    const float4 b = *(const float4*)&part[i];
    const float4 r = {a.x + b.x, a.y + b.y, a.z + b.z, a.w + b.w};
    *(float4*)&acc[i] = r;
}

// ---------------- persistent single-workgroup scan ----------------
// 512 threads * 8 neurons. Prefetched cur_x rows, flat spike list rebuilt
// per step (deterministic sorted compaction), 4-wide batched column gather.
template <int USE_WST>
__global__ __launch_bounds__(512) void k_scan(const float* __restrict__ WsT,
                                              const float* __restrict__ W,
                                              float* __restrict__ spk_out,
                                              float* __restrict__ mem_out) {
    __shared__ int lst[N_SIZE];
    __shared__ int wcnt[8];
    const int tid = threadIdx.x;
    const int wave = tid >> 6;
    const int lane = tid & 63;
    const int base = tid << 3;   // neurons base..base+7
    const unsigned long long below = (lane == 0) ? 0ULL : (~0ULL >> (64 - lane));

    float4 m0 = {0.f, 0.f, 0.f, 0.f}, m1 = {0.f, 0.f, 0.f, 0.f};
    int cnt = 0;

    float4 cn0 = *(const float4*)&mem_out[base];
    float4 cn1 = *(const float4*)&mem_out[base + 4];

    for (int t = 0; t < N_STEPS; ++t) {
        float4 c0 = cn0, c1 = cn1;
        // prefetch next cur_x row (hides HBM latency under this step's work)
        const int tn = (t + 1 < N_STEPS) ? (t + 1) : t;
        const float* nr = &mem_out[(size_t)tn * N_SIZE + base];
        cn0 = *(const float4*)&nr[0];
        cn1 = *(const float4*)&nr[4];

        // ---- 4-wide batched gather over flat spike list ----
        for (int i = 0; i < cnt; i += 4) {
            const int s0 = lst[i];
            const bool v1 = (i + 1 < cnt), v2 = (i + 2 < cnt), v3 = (i + 3 < cnt);
            const int s1 = v1 ? lst[i + 1] : s0;
            const int s2 = v2 ? lst[i + 2] : s0;
            const int s3 = v3 ? lst[i + 3] : s0;
            const float f1 = v1 ? 1.f : 0.f;
            const float f2 = v2 ? 1.f : 0.f;
            const float f3 = v3 ? 1.f : 0.f;
            float4 w0a, w0b, w1a, w1b, w2a, w2b, w3a, w3b;
            if (USE_WST) {
                const float* p0 = &WsT[(size_t)s0 * N_SIZE + base];
                const float* p1 = &WsT[(size_t)s1 * N_SIZE + base];
                const float* p2 = &WsT[(size_t)s2 * N_SIZE + base];
                const float* p3 = &WsT[(size_t)s3 * N_SIZE + base];
                w0a = *(const float4*)&p0[0]; w0b = *(const float4*)&p0[4];
                w1a = *(const float4*)&p1[0]; w1b = *(const float4*)&p1[4];
                w2a = *(const float4*)&p2[0]; w2b = *(const float4*)&p2[4];
                w3a = *(const float4*)&p3[0]; w3b = *(const float4*)&p3[4];
            } else {
#pragma unroll
                for (int j = 0; j < 4; ++j) {
                    F4E(w0a, j) = W[(size_t)(base + j) * WROW + N_SIZE + s0];
                    F4E(w0b, j) = W[(size_t)(base + 4 + j) * WROW + N_SIZE + s0];
                    F4E(w1a, j) = W[(size_t)(base + j) * WROW + N_SIZE + s1];
                    F4E(w1b, j) = W[(size_t)(base + 4 + j) * WROW + N_SIZE + s1];
                    F4E(w2a, j) = W[(size_t)(base + j) * WROW + N_SIZE + s2];
                    F4E(w2b, j) = W[(size_t)(base + 4 + j) * WROW + N_SIZE + s2];
                    F4E(w3a, j) = W[(size_t)(base + j) * WROW + N_SIZE + s3];
                    F4E(w3b, j) = W[(size_t)(base + 4 + j) * WROW + N_SIZE + s3];
                }
            }
            c0.x += w0a.x; c0.y += w0a.y; c0.z += w0a.z; c0.w += w0a.w;
            c1.x += w0b.x; c1.y += w0b.y; c1.z += w0b.z; c1.w += w0b.w;
            c0.x = fmaf(f1, w1a.x, c0.x); c0.y = fmaf(f1, w1a.y, c0.y);
            c0.z = fmaf(f1, w1a.z, c0.z); c0.w = fmaf(f1, w1a.w, c0.w);
            c1.x = fmaf(f1, w1b.x, c1.x); c1.y = fmaf(f1, w1b.y, c1.y);
            c1.z = fmaf(f1, w1b.z, c1.z); c1.w = fmaf(f1, w1b.w, c1.w);
            c0.x = fmaf(f2, w2a.x, c0.x); c0.y = fmaf(f2, w2a.y, c0.y);
            c0.z = fmaf(f2, w2a.z, c0.z); c0.w = fmaf(f2, w2a.w, c0.w);
            c1.x = fmaf(f2, w2b.x, c1.x); c1.y = fmaf(f2, w2b.y, c1.y);
            c1.z = fmaf(f2, w2b.z, c1.z); c1.w = fmaf(f2, w2b.w, c1.w);
            c0.x = fmaf(f3, w3a.x, c0.x); c0.y = fmaf(f3, w3a.y, c0.y);
            c0.z = fmaf(f3, w3a.z, c0.z); c0.w = fmaf(f3, w3a.w, c0.w);
            c1.x = fmaf(f3, w3b.x, c1.x); c1.y = fmaf(f3, w3b.y, c1.y);
            c1.z = fmaf(f3, w3b.z, c1.z); c1.w = fmaf(f3, w3b.w, c1.w);
        }

        m0.x += c0.x; m0.y += c0.y; m0.z += c0.z; m0.w += c0.w;
        m1.x += c1.x; m1.y += c1.y; m1.z += c1.z; m1.w += c1.w;

        const bool s0b = m0.x > THRESH, s1b = m0.y > THRESH;
        const bool s2b = m0.z > THRESH, s3b = m0.w > THRESH;
        const bool s4b = m1.x > THRESH, s5b = m1.y > THRESH;
        const bool s6b = m1.z > THRESH, s7b = m1.w > THRESH;
        m0.x -= s0b ? THRESH : 0.f;  m0.y -= s1b ? THRESH : 0.f;
        m0.z -= s2b ? THRESH : 0.f;  m0.w -= s3b ? THRESH : 0.f;
        m1.x -= s4b ? THRESH : 0.f;  m1.y -= s5b ? THRESH : 0.f;
        m1.z -= s6b ? THRESH : 0.f;  m1.w -= s7b ? THRESH : 0.f;

        const float4 sp0 = {s0b ? 1.f : 0.f, s1b ? 1.f : 0.f,
                            s2b ? 1.f : 0.f, s3b ? 1.f : 0.f};
        const float4 sp1 = {s4b ? 1.f : 0.f, s5b ? 1.f : 0.f,
                            s6b ? 1.f : 0.f, s7b ? 1.f : 0.f};
        float* srow = &spk_out[(size_t)t * N_SIZE + base];
        float* mrow = &mem_out[(size_t)t * N_SIZE + base];
        *(float4*)&srow[0] = sp0;
        *(float4*)&srow[4] = sp1;
        *(float4*)&mrow[0] = m0;
        *(float4*)&mrow[4] = m1;

        // ---- deterministic sorted compaction (2 barriers) ----
        const unsigned long long B0 = __ballot(s0b), B1 = __ballot(s1b);
        const unsigned long long B2 = __ballot(s2b), B3 = __ballot(s3b);
        const unsigned long long B4 = __ballot(s4b), B5 = __ballot(s5b);
        const unsigned long long B6 = __ballot(s6b), B7 = __ballot(s7b);
        const int pre = __popcll(B0 & below) + __popcll(B1 & below) +
                        __popcll(B2 & below) + __popcll(B3 & below) +
                        __popcll(B4 & below) + __popcll(B5 & below) +
                        __popcll(B6 & below) + __popcll(B7 & below);
        if (lane == 0)
            wcnt[wave] = __popcll(B0) + __popcll(B1) + __popcll(B2) + __popcll(B3) +
                         __popcll(B4) + __popcll(B5) + __popcll(B6) + __popcll(B7);
        __syncthreads();   // wcnt visible; all gather reads of lst done

        int woff = 0, total = 0;
#pragma unroll
        for (int w = 0; w < 8; ++w) {
            const int cw = wcnt[w];
            if (w < wave) woff += cw;
            total += cw;
        }
        int off = woff + pre;
        if (s0b) lst[off++] = base + 0;
        if (s1b) lst[off++] = base + 1;
        if (s2b) lst[off++] = base + 2;
        if (s3b) lst[off++] = base + 3;
        if (s4b) lst[off++] = base + 4;
        if (s5b) lst[off++] = base + 5;
        if (s6b) lst[off++] = base + 6;
        if (s7b) lst[off++] = base + 7;
        __syncthreads();   // list ready for next step

        cnt = total;
    }
}

extern "C" void kernel_launch(void* const* d_in, const int* in_sizes, int n_in,
                              void* d_out, int out_size, void* d_ws, size_t ws_size,
                              hipStream_t stream) {
    const float* x = (const float*)d_in[0];
    const float* W = (const float*)d_in[1];
    float* spk_out = (float*)d_out;
    float* mem_out = spk_out + (size_t)N_STEPS * N_SIZE;
    float* WsT = (float*)d_ws;
    const bool use_wst = ws_size >= (size_t)N_SIZE * N_SIZE * sizeof(float);

    if (use_wst)
        k_transpose<<<dim3(N_SIZE / 32, N_SIZE / 32), dim3(32, 8), 0, stream>>>(W, WsT);

    // split-K partials: z=0 -> mem_out, z=1 -> spk_out (both overwritten later)
    k_gemm<<<dim3(N_SIZE / BN, N_STEPS / BM, 2), 128, 0, stream>>>(x, W, mem_out, spk_out);
    k_reduce<<<(N_STEPS * N_SIZE) / (256 * 4), 256, 0, stream>>>(mem_out, spk_out);

    if (use_wst)
        k_scan<1><<<1, 512, 0, stream>>>(WsT, W, spk_out, mem_out);
    else
        k_scan<0><<<1, 512, 0, stream>>>(WsT, W, spk_out, mem_out);
}